// Round 11
// baseline (74.123 us; speedup 1.0000x reference)
//
#include <hip/hip_runtime.h>

// out[b][o] = sum_{i,m} a0[b,i]*D[b,m]*T[i][m][o],  D[b,m]=a1*a2*a3, m=(j,k,l)
// Single real dispatch: 2247 one-wave blocks; each wave computes its own
// df/a0 locally (no k_pre), streams T via v_mfma_f32_32x32x16_bf16 (r8 loop
// verbatim), atomically accumulates NT partial tiles, and the LAST block
// folds tiles -> out (vmcnt-ordered, fence-free; all tile accesses atomic).
#define HSZ 32
#define HP1 33
#define M3 35937            // 33^3 (flattened j,k,l)
#define TI_STRIDE 1149984   // 33^3 * 32 floats (stride of T over i)
#define NBLK 2247           // one wave per block
#define NT 32               // partial tiles (contention 2247/32 ~ 70)

// ws: tiles @ 0 : NT*1024 floats = 131072 B ; cnt @ 131072 : 1 uint
#define OFF_CNT 131072

typedef short bf16x8 __attribute__((ext_vector_type(8)));
typedef float f32x16 __attribute__((ext_vector_type(16)));

__device__ inline short f2bf(float f) {
  unsigned u = __builtin_bit_cast(unsigned, f);
  u += 0x7FFFu + ((u >> 16) & 1u);   // round-to-nearest-even
  return (short)(u >> 16);
}

__global__ __launch_bounds__(64) void k_main(const float* __restrict__ T,
                                             const float* __restrict__ nh,
                                             float* __restrict__ tiles,
                                             unsigned* __restrict__ cnt,
                                             float* __restrict__ out) {
  __shared__ float a0s[HP1 * 32];  // a0s[i*32+b]; row 32 = 1.0 (bias)
  const int blk = blockIdx.x;
  const int m0 = blk * 16;
  const int l = (int)threadIdx.x;  // 0..63
  const int bo = l & 31;           // A row (b) / B col (o)
  const int g = l >> 5;            // k-group: k = 8*g + e

  // Per-lane T element offsets (clamped in the tail; df=0 there)
  size_t toff[8];
#pragma unroll
  for (int e = 0; e < 8; ++e) {
    int mm = m0 + 8 * g + e;
    if (mm > M3 - 1) mm = M3 - 1;
    toff[e] = (size_t)mm * 32 + bo;
  }

  // issue the first T row load NOW; prologue flies underneath it
  float tv[8];
#pragma unroll
  for (int e = 0; e < 8; ++e) tv[e] = T[toff[e]];

  // stage a0 transposed into LDS: lanes 0..31 write their b-row (one wave,
  // lockstep -> no barrier; write bank = bo -> conflict-free)
  if (g == 0) {
    for (int i = 0; i < HSZ; ++i) a0s[i * 32 + bo] = nh[bo * 128 + i];
    a0s[HSZ * 32 + bo] = 1.0f;  // bias row
  }

  // A-side fragment df[e] = a1*a2*a3 for this wave's 8 m's (L1/L2-hot nh)
  float df[8];
#pragma unroll
  for (int e = 0; e < 8; ++e) {
    const int mm = m0 + 8 * g + e;
    const bool valid = mm < M3;
    const int mc = valid ? mm : (M3 - 1);
    const int j = mc / 1089;
    const int r = mc - j * 1089;
    const int kk = r / 33;
    const int ll = r - kk * 33;
    const float a1 = (j < HSZ) ? nh[bo * 128 + 32 + j] : 1.0f;
    const float a2 = (kk < HSZ) ? nh[bo * 128 + 64 + kk] : 1.0f;
    const float a3 = (ll < HSZ) ? nh[bo * 128 + 96 + ll] : 1.0f;
    df[e] = valid ? (a1 * a2 * a3) : 0.0f;
  }

  f32x16 acc = {};
  float a0c = a0s[bo];

  // r8's dist-1 rolling-prefetch loop, verbatim (a0 now from LDS)
  for (int i = 0; i < HP1; ++i) {
    float tn[8];
    float a0n = 0.f;
    if (i < HP1 - 1) {
      const float* Tn = T + (size_t)(i + 1) * TI_STRIDE;
#pragma unroll
      for (int e = 0; e < 8; ++e) tn[e] = Tn[toff[e]];
      a0n = a0s[(i + 1) * 32 + bo];
    }
    bf16x8 af, bfr;
#pragma unroll
    for (int e = 0; e < 8; ++e) {
      af[e]  = f2bf(a0c * df[e]);
      bfr[e] = f2bf(tv[e]);
    }
    acc = __builtin_amdgcn_mfma_f32_32x32x16_bf16(af, bfr, acc, 0, 0, 0);
#pragma unroll
    for (int e = 0; e < 8; ++e) tv[e] = tn[e];
    a0c = a0n;
  }

  // Atomic partial-tile accumulate.
  // C/D layout (m74/m101): col=lane&31, row=(r&3)+8*(r>>2)+4*(lane>>5)
  float* tp = tiles + (size_t)(blk & (NT - 1)) * 1024;
#pragma unroll
  for (int r = 0; r < 16; ++r) {
    const int brow = (r & 3) + 8 * (r >> 2) + 4 * g;
    atomicAdd(tp + brow * 32 + bo, acc[r]);
  }

  // Order my tile atomics before the arrival increment (completion only --
  // atomics are device-coherent; no L2 flush needed, unlike __threadfence).
  asm volatile("s_waitcnt vmcnt(0)" ::: "memory");
  unsigned done = 0;
  if (l == 0) done = atomicAdd(cnt, 1u);
  done = __builtin_amdgcn_readfirstlane(done);
  if (done == NBLK - 1) {
    // All blocks' vmcnt(0)+increment happened -> their tile atomics are
    // globally performed. Read tiles coherently (atomic read = add 0).
    float v[16];
#pragma unroll
    for (int q = 0; q < 16; ++q) v[q] = 0.f;
    for (int t = 0; t < NT; ++t) {
      float* base = tiles + (size_t)t * 1024;
#pragma unroll
      for (int q = 0; q < 16; ++q) {
        v[q] += atomicAdd(base + q * 64 + l, 0.0f);
      }
    }
#pragma unroll
    for (int q = 0; q < 16; ++q) out[q * 64 + l] = v[q];
  }
}

extern "C" void kernel_launch(void* const* d_in, const int* in_sizes, int n_in,
                              void* d_out, int out_size, void* d_ws, size_t ws_size,
                              hipStream_t stream) {
  const float* nh = (const float*)d_in[0];  // [32,4,32]
  const float* T  = (const float*)d_in[1];  // [33,33,33,33,32]
  float* out = (float*)d_out;               // [32,32] fp32
  char* ws = (char*)d_ws;
  float* tiles  = (float*)ws;
  unsigned* cnt = (unsigned*)(ws + OFF_CNT);

  hipMemsetAsync(ws, 0, OFF_CNT + sizeof(unsigned), stream);
  k_main<<<NBLK, 64, 0, stream>>>(T, nh, tiles, cnt, out);
}

// Round 12
// 42.631 us; speedup vs baseline: 1.7387x; 1.7387x over previous
//
#include <hip/hip_runtime.h>
#include <hip/hip_bf16.h>

// Problem constants
#define HSZ 32
#define HP1 33
#define M3 35937            // 33^3 (flattened j,k,l)
#define M3P 35952           // padded to multiple of 16 (2247*16)
#define TI_STRIDE 1149984   // 33^3 * 32 floats (stride of T over i)
#define NBLK 2247           // M3P / 16, one wave per block
#define NT 64               // partial output tiles (atomic contention 2247/64 ~ 35)

// ws layout (bytes):
//   a0T   @ 0        : 33*32 floats (a0 transposed, [i][b])
//   D     @ 8192     : 32*35952 floats = 4,601,856 B (zero-padded tail)
//   tiles @ 4610048  : 64*1024 floats = 262,144 B      total ~4.9 MB
#define OFF_A0T   0
#define OFF_D     8192
#define OFF_TILES 4610048

typedef short bf16x8 __attribute__((ext_vector_type(8)));
typedef float f32x16 __attribute__((ext_vector_type(16)));

// SINGLE CHANGE vs round-8 baseline: scalar cast instead of bit-hack so the
// compiler pairs conversions into v_cvt_pk_bf16_f32 (4 instrs/frag vs 32).
__device__ inline short f2bf(float f) {
  __hip_bfloat16 h = __float2bfloat16(f);  // RTNE
  return __builtin_bit_cast(short, h);
}

// Prologue: D[b][m] = a1*a2*a3 (0 in pad), a0T[i][b], zero the partial tiles.
__global__ __launch_bounds__(256) void k_pre(const float* __restrict__ nh,
                                             float* __restrict__ a0T,
                                             float* __restrict__ D,
                                             float* __restrict__ tiles) {
  const int b = blockIdx.y;
  const int m = blockIdx.x * 256 + threadIdx.x;
  if (m < M3P) {
    float v = 0.f;
    if (m < M3) {
      const int j = m / 1089;
      const int r = m - j * 1089;
      const int k = r / 33;
      const int l = r - k * 33;
      const float a1 = (j < HSZ) ? nh[(b * 4 + 1) * HSZ + j] : 1.0f;
      const float a2 = (k < HSZ) ? nh[(b * 4 + 2) * HSZ + k] : 1.0f;
      const float a3 = (l < HSZ) ? nh[(b * 4 + 3) * HSZ + l] : 1.0f;
      v = a1 * a2 * a3;
    }
    D[(size_t)b * M3P + m] = v;
  }
  if (blockIdx.x == 0 && threadIdx.x < HP1) {
    const int i = threadIdx.x;
    a0T[i * 32 + b] = (i < HSZ) ? nh[(b * 4 + 0) * HSZ + i] : 1.0f;
  }
  if (b == 1 && blockIdx.x < 64) {  // 64 blocks * 256 threads * 16B = 256 KB
    ((float4*)tiles)[blockIdx.x * 256 + threadIdx.x] =
        make_float4(0.f, 0.f, 0.f, 0.f);
  }
}

// Main: one wave per block; block owns m-chunk [m0, m0+16).
// acc[32b x 32o] += sum_i sum_{mm} (a0[b,i]*D[b,mm]) * T[i][mm][o] via
// v_mfma_f32_32x32x16_bf16. T is read exactly once device-wide, coalesced.
__global__ __launch_bounds__(64) void k_main(const float* __restrict__ T,
                                             const float* __restrict__ a0T,
                                             const float* __restrict__ D,
                                             float* __restrict__ tiles) {
  const int blk = blockIdx.x;
  const int m0 = blk * 16;
  const int l = (int)threadIdx.x;  // 0..63
  const int bo = l & 31;           // A row (b) / B col (o)
  const int g = l >> 5;            // k-group: k = 8*g + e

  // A-side D fragment (fp32, reused across all 33 i): D[bo][m0+8g+e]
  const float* dp = D + (size_t)bo * M3P + m0 + 8 * g;
  float df[8];
  *(float4*)(df)     = *(const float4*)(dp);
  *(float4*)(df + 4) = *(const float4*)(dp + 4);

  // Per-lane T element offsets for the 8 k's (clamped in the zero-padded tail)
  size_t toff[8];
#pragma unroll
  for (int e = 0; e < 8; ++e) {
    int mm = m0 + 8 * g + e;
    if (mm > M3 - 1) mm = M3 - 1;  // A-frag is 0 there (D pad), value ignored
    toff[e] = (size_t)mm * 32 + bo;
  }

  f32x16 acc = {};

  // software pipeline: loads for i+1 in flight during cvt+MFMA of i
  float tv[8];
#pragma unroll
  for (int e = 0; e < 8; ++e) tv[e] = T[toff[e]];
  float a0c = a0T[bo];

  for (int i = 0; i < HP1; ++i) {
    float tn[8];
    float a0n = 0.f;
    if (i < HP1 - 1) {
      const float* Tn = T + (size_t)(i + 1) * TI_STRIDE;
#pragma unroll
      for (int e = 0; e < 8; ++e) tn[e] = Tn[toff[e]];
      a0n = a0T[(i + 1) * 32 + bo];
    }
    bf16x8 af, bfr;
#pragma unroll
    for (int e = 0; e < 8; ++e) {
      af[e]  = f2bf(a0c * df[e]);
      bfr[e] = f2bf(tv[e]);
    }
    acc = __builtin_amdgcn_mfma_f32_32x32x16_bf16(af, bfr, acc, 0, 0, 0);
#pragma unroll
    for (int e = 0; e < 8; ++e) tv[e] = tn[e];
    a0c = a0n;
  }

  // Accumulate into one of NT partial tiles.
  // C/D layout (verified m74/m101): col=lane&31, row=(r&3)+8*(r>>2)+4*(lane>>5)
  float* tp = tiles + (size_t)(blk & (NT - 1)) * 1024;
#pragma unroll
  for (int r = 0; r < 16; ++r) {
    const int brow = (r & 3) + 8 * (r >> 2) + 4 * g;
    atomicAdd(tp + brow * 32 + bo, acc[r]);
  }
}

// Final reduce: out[idx] = sum over NT tiles.
__global__ __launch_bounds__(256) void k_red(const float* __restrict__ tiles,
                                             float* __restrict__ out) {
  const int idx = blockIdx.x * 256 + (int)threadIdx.x;
  float s = 0.f;
  for (int t = 0; t < NT; ++t) s += tiles[(size_t)t * 1024 + idx];
  out[idx] = s;
}

extern "C" void kernel_launch(void* const* d_in, const int* in_sizes, int n_in,
                              void* d_out, int out_size, void* d_ws, size_t ws_size,
                              hipStream_t stream) {
  const float* nh = (const float*)d_in[0];  // [32,4,32]
  const float* T  = (const float*)d_in[1];  // [33,33,33,33,32]
  float* out = (float*)d_out;               // [32,32] fp32
  char* ws = (char*)d_ws;
  float* a0T   = (float*)(ws + OFF_A0T);
  float* D     = (float*)(ws + OFF_D);
  float* tiles = (float*)(ws + OFF_TILES);

  k_pre<<<dim3(141, 32), 256, 0, stream>>>(nh, a0T, D, tiles);
  k_main<<<NBLK, 64, 0, stream>>>(T, a0T, D, tiles);
  k_red<<<4, 256, 0, stream>>>(tiles, out);
}